// Round 1
// baseline (2918.454 us; speedup 1.0000x reference)
//
#include <hip/hip_runtime.h>
#include <math.h>

namespace {

constexpr int kN = 1024;      // tokens
constexpr int kM = 64;        // multiplicity
constexpr int kP = 64;        // PE dim
constexpr int kD = 256;       // 4*M
constexpr float kEps = 1e-5f;
constexpr int kFN = 1024;     // FFT length

__device__ __forceinline__ float sigmoidf(float v) { return 1.0f / (1.0f + expf(-v)); }

// ---------------------------------------------------------------- init
__global__ void k_zero(float* p) { p[threadIdx.x] = 0.0f; }

// s0[n, m] = sum_p (pe[n,p] + tok_emb[tt[n],p]) * Wf[p,m]
__global__ void k_s0(const float* __restrict__ tok_emb, const float* __restrict__ Wf,
                     float* __restrict__ s0) {
  __shared__ float f[kP];
  const int n = blockIdx.x;
  const int t = threadIdx.x;                       // 64 threads
  const int tt = (n == kN - 1) ? 2 : (n & 1);
  const int j = t >> 1;
  const float cexp = (float)(-9.210340371976184 / 64.0);   // -ln(10000)/P
  const float divj = expf((float)(2 * j) * cexp);
  const float ang = (float)n * divj;
  const float pe = (t & 1) ? cosf(ang) : sinf(ang);
  f[t] = pe + tok_emb[tt * kP + t];
  __syncthreads();
  float acc = 0.0f;
#pragma unroll 8
  for (int p = 0; p < kP; ++p) acc = fmaf(f[p], Wf[p * kM + t], acc);
  s0[n * kM + t] = acc;
}

// h[r, m, 0..3] = (s0[n,m], x[r]*wv[m])
__global__ void k_h0(const float* __restrict__ x, const float* __restrict__ wv,
                     const float* __restrict__ s0, float* __restrict__ h) {
  const int idx = blockIdx.x * 256 + threadIdx.x;  // r*64 + m
  const int r = idx >> 6;
  const int m = idx & 63;
  const int n = r & (kN - 1);
  const float w = wv[m];
  float4 o;
  o.x = s0[n * kM + m];
  o.y = x[r * 3 + 0] * w;
  o.z = x[r * 3 + 1] * w;
  o.w = x[r * 3 + 2] * w;
  ((float4*)h)[idx] = o;
}

// ---------------------------------------------------------------- FFT (radix-2, no bit-reversal)
__device__ void fft_build_tw(float2* tw) {
  for (int j = threadIdx.x; j < kFN / 2; j += 256) {
    float s, c;
    sincosf(-6.283185307179586f * (float)j / (float)kFN, &s, &c);
    tw[j].x = c; tw[j].y = s;
  }
}

// forward DIF: natural in -> bit-reversed out
__device__ void fft_dif(float2* z, const float2* tw) {
  for (int span = kFN / 2; span >= 1; span >>= 1) {
    const int tm = (kFN / 2) / span;
    __syncthreads();
#pragma unroll
    for (int it = 0; it < 2; ++it) {
      const int p = threadIdx.x + it * 256;
      const int k = p & (span - 1);
      const int i = ((p & ~(span - 1)) << 1) | k;
      const float2 u = z[i];
      const float2 v = z[i + span];
      const float2 w = tw[k * tm];
      float2 sum, d, o;
      sum.x = u.x + v.x; sum.y = u.y + v.y;
      d.x = u.x - v.x;   d.y = u.y - v.y;
      o.x = d.x * w.x - d.y * w.y;
      o.y = d.x * w.y + d.y * w.x;
      z[i] = sum;
      z[i + span] = o;
    }
  }
}

// inverse DIT: bit-reversed in -> natural out (caller scales by 1/N)
__device__ void fft_dit_inv(float2* z, const float2* tw) {
  for (int span = 1; span <= kFN / 2; span <<= 1) {
    const int tm = (kFN / 2) / span;
    __syncthreads();
#pragma unroll
    for (int it = 0; it < 2; ++it) {
      const int p = threadIdx.x + it * 256;
      const int k = p & (span - 1);
      const int i = ((p & ~(span - 1)) << 1) | k;
      const float2 w = tw[k * tm];         // conj used below
      const float2 v = z[i + span];
      float2 tv, a, bq;
      tv.x = v.x * w.x + v.y * w.y;
      tv.y = v.y * w.x - v.x * w.y;
      const float2 u = z[i];
      a.x = u.x + tv.x;  a.y = u.y + tv.y;
      bq.x = u.x - tv.x; bq.y = u.y - tv.y;
      z[i] = a;
      z[i + span] = bq;
    }
  }
}

// filter spectrum, stored in DIF (bit-reversed) order; one block per channel
__global__ __launch_bounds__(256) void k_kf(const float* __restrict__ filt, int H,
                                            float2* __restrict__ kf) {
  __shared__ float2 z[kFN];
  __shared__ float2 tw[kFN / 2];
  const int c = blockIdx.x;
  fft_build_tw(tw);
  for (int n = threadIdx.x; n < kFN; n += 256) {
    z[n].x = filt[n * H + c];
    z[n].y = 0.0f;
  }
  fft_dif(z, tw);
  __syncthreads();
  for (int j = threadIdx.x; j < kFN; j += 256) kf[c * kFN + j] = z[j];
}

// circular conv in-place on kv_t rows; one block per (b, c)
__global__ __launch_bounds__(256) void k_conv(float* kvt, const float2* __restrict__ kf, int H) {
  __shared__ float2 z[kFN];
  __shared__ float2 tw[kFN / 2];
  const int row = blockIdx.x;              // b*H + c
  const int c = row % H;
  float* sig = kvt + (size_t)row * kFN;
  fft_build_tw(tw);
  for (int n = threadIdx.x; n < kFN; n += 256) {
    z[n].x = sig[n];
    z[n].y = 0.0f;
  }
  fft_dif(z, tw);
  __syncthreads();
  for (int j = threadIdx.x; j < kFN; j += 256) {
    const float2 a = z[j];
    const float2 b = kf[c * kFN + j];
    float2 o;
    o.x = a.x * b.x - a.y * b.y;
    o.y = a.x * b.y + a.y * b.x;
    z[j] = o;
  }
  fft_dit_inv(z, tw);
  __syncthreads();
  const float s = 1.0f / (float)kFN;
  for (int n = threadIdx.x; n < kFN; n += 256) sig[n] = z[n].x * s;
}

// ---------------------------------------------------------------- GEMM 1: q/k/v fused
// q_t[(b*H+c)*N+n] = (h@Wq)^T ; kv_t = ((h@Wk)*(h@Wv))^T
__global__ __launch_bounds__(256) void k_qkv(const float* __restrict__ h,
    const float* __restrict__ Wq, const float* __restrict__ Wk, const float* __restrict__ Wvm,
    int H, float* __restrict__ qt, float* __restrict__ kvt) {
  __shared__ float smem[4352];             // staging 16x68 + 3*16x64 ; epilogue 64x68
  float* As  = smem;
  float* Ws0 = smem + 1088;
  float* Ws1 = smem + 2112;
  float* Ws2 = smem + 3136;
  const int t = threadIdx.x;
  const int r0 = blockIdx.x * 64;
  const int c0 = blockIdx.y * 64;
  const int tx = t & 15, ty = t >> 4;
  const int arow = t >> 2, akq = t & 3;
  float accq[4][4] = {}, acck[4][4] = {}, accv[4][4] = {};
  const float* hA = h + (size_t)(r0 + arow) * kD + akq * 4;
  for (int kk = 0; kk < kD; kk += 16) {
    __syncthreads();
    const float4 av = *(const float4*)(hA + kk);
    As[(akq * 4 + 0) * 68 + arow] = av.x;
    As[(akq * 4 + 1) * 68 + arow] = av.y;
    As[(akq * 4 + 2) * 68 + arow] = av.z;
    As[(akq * 4 + 3) * 68 + arow] = av.w;
#pragma unroll
    for (int it = 0; it < 4; ++it) {
      const int idx = t + it * 256;
      const int wk = idx >> 6, wc = idx & 63;
      const int col = c0 + wc;
      const int g = (kk + wk) * H + col;
      const bool ok = col < H;
      Ws0[wk * 64 + wc] = ok ? Wq[g] : 0.0f;
      Ws1[wk * 64 + wc] = ok ? Wk[g] : 0.0f;
      Ws2[wk * 64 + wc] = ok ? Wvm[g] : 0.0f;
    }
    __syncthreads();
#pragma unroll
    for (int k = 0; k < 16; ++k) {
      const float4 a4 = *(const float4*)(As + k * 68 + ty * 4);
      const float4 q4 = *(const float4*)(Ws0 + k * 64 + tx * 4);
      const float4 k4 = *(const float4*)(Ws1 + k * 64 + tx * 4);
      const float4 v4 = *(const float4*)(Ws2 + k * 64 + tx * 4);
      const float a[4]  = {a4.x, a4.y, a4.z, a4.w};
      const float bq[4] = {q4.x, q4.y, q4.z, q4.w};
      const float bk[4] = {k4.x, k4.y, k4.z, k4.w};
      const float bv[4] = {v4.x, v4.y, v4.z, v4.w};
#pragma unroll
      for (int i = 0; i < 4; ++i)
#pragma unroll
        for (int j = 0; j < 4; ++j) {
          accq[i][j] = fmaf(a[i], bq[j], accq[i][j]);
          acck[i][j] = fmaf(a[i], bk[j], acck[i][j]);
          accv[i][j] = fmaf(a[i], bv[j], accv[i][j]);
        }
    }
  }
  const int bidx = r0 >> 10;
  const int n0 = r0 & 1023;
  const size_t obase = ((size_t)(bidx * H) << 10) + n0;
  // ---- transpose+store q
  __syncthreads();
#pragma unroll
  for (int i = 0; i < 4; ++i)
#pragma unroll
    for (int j = 0; j < 4; ++j)
      smem[(tx * 4 + j) * 68 + ty * 4 + i] = accq[i][j];
  __syncthreads();
  {
    const int cl = t >> 2, qq = t & 3;
    if (c0 + cl < H) {
      float* dst = qt + obase + ((size_t)(c0 + cl) << 10) + qq * 16;
      const float* src = smem + cl * 68 + qq * 16;
#pragma unroll
      for (int u = 0; u < 4; ++u) ((float4*)dst)[u] = *(const float4*)(src + u * 4);
    }
  }
  // ---- transpose+store kv = k*v
  __syncthreads();
#pragma unroll
  for (int i = 0; i < 4; ++i)
#pragma unroll
    for (int j = 0; j < 4; ++j)
      smem[(tx * 4 + j) * 68 + ty * 4 + i] = acck[i][j] * accv[i][j];
  __syncthreads();
  {
    const int cl = t >> 2, qq = t & 3;
    if (c0 + cl < H) {
      float* dst = kvt + obase + ((size_t)(c0 + cl) << 10) + qq * 16;
      const float* src = smem + cl * 68 + qq * 16;
#pragma unroll
      for (int u = 0; u < 4; ++u) ((float4*)dst)[u] = *(const float4*)(src + u * 4);
    }
  }
}

// ---------------------------------------------------------------- GEMM 2: h += (q*conv) @ Wo
__global__ __launch_bounds__(256) void k_mix(const float* __restrict__ qt,
    const float* __restrict__ convt, const float* __restrict__ Wo, int H,
    float* __restrict__ h) {
  __shared__ float smem[2112];
  float* As = smem;        // [16][68], k-major A = q*conv
  float* Ws = smem + 1088; // [16][64]
  const int t = threadIdx.x;
  const int r0 = blockIdx.x * 64;
  const int d0 = blockIdx.y * 64;
  const int tx = t & 15, ty = t >> 4;
  const int bidx = r0 >> 10;
  const int n0 = r0 & 1023;
  const size_t sbase = ((size_t)(bidx * H) << 10) + n0;
  float acc[4][4] = {};
  const int KT = (H + 15) / 16;
  for (int kt = 0; kt < KT; ++kt) {
    const int ck0 = kt * 16;
    __syncthreads();
    {
      const int cl = t >> 4;
      const int n4 = (t & 15) * 4;
      const int c = ck0 + cl;
      float4 prod = {0.f, 0.f, 0.f, 0.f};
      if (c < H) {
        const size_t o = sbase + ((size_t)c << 10) + n4;
        const float4 qv = *(const float4*)(qt + o);
        const float4 cv = *(const float4*)(convt + o);
        prod.x = qv.x * cv.x; prod.y = qv.y * cv.y;
        prod.z = qv.z * cv.z; prod.w = qv.w * cv.w;
      }
      *(float4*)(As + cl * 68 + n4) = prod;
    }
#pragma unroll
    for (int it = 0; it < 4; ++it) {
      const int idx = t + it * 256;
      const int wk = idx >> 6, wc = idx & 63;
      const int c = ck0 + wk;
      Ws[wk * 64 + wc] = (c < H) ? Wo[c * kD + d0 + wc] : 0.0f;
    }
    __syncthreads();
#pragma unroll
    for (int k = 0; k < 16; ++k) {
      const float4 a4 = *(const float4*)(As + k * 68 + ty * 4);
      const float4 b4 = *(const float4*)(Ws + k * 64 + tx * 4);
      const float a[4]  = {a4.x, a4.y, a4.z, a4.w};
      const float bb[4] = {b4.x, b4.y, b4.z, b4.w};
#pragma unroll
      for (int i = 0; i < 4; ++i)
#pragma unroll
        for (int j = 0; j < 4; ++j)
          acc[i][j] = fmaf(a[i], bb[j], acc[i][j]);
    }
  }
#pragma unroll
  for (int i = 0; i < 4; ++i) {
    float4* hp = (float4*)(h + (size_t)(r0 + ty * 4 + i) * kD + d0 + tx * 4);
    float4 hv = *hp;
    hv.x += acc[i][0]; hv.y += acc[i][1]; hv.z += acc[i][2]; hv.w += acc[i][3];
    *hp = hv;
  }
}

// ---------------------------------------------------------------- GEMM 3: reg_linear + BN stats
__global__ __launch_bounds__(256) void k_reg(const float* __restrict__ h,
    const float* __restrict__ Wm0, const float* __restrict__ Wm1,
    float* __restrict__ y, float* __restrict__ stats) {
  __shared__ float smem[6400];
  float* As  = smem;          // (ml*4+comp)*68 + row
  float* W0s = smem + 4352;
  float* W1s = smem + 5376;
  const int t = threadIdx.x;
  const int r0 = blockIdx.x * 64;
  const int tx = t & 15, ty = t >> 4;
  const int row = t >> 2, f4 = t & 3;
  float acc0[4][4] = {}, acc1[4][4] = {}, acc2[4][4] = {}, acc3[4][4] = {};
  const float* hrow = h + (size_t)(r0 + row) * kD;
  for (int kt = 0; kt < 4; ++kt) {
    const int m0 = kt * 16;
    __syncthreads();
#pragma unroll
    for (int it = 0; it < 4; ++it) {
      const int o = f4 * 16 + it * 4;
      const float4 v = *(const float4*)(hrow + m0 * 4 + o);
      const int ml = o >> 2;
      As[(ml * 4 + 0) * 68 + row] = v.x;
      As[(ml * 4 + 1) * 68 + row] = v.y;
      As[(ml * 4 + 2) * 68 + row] = v.z;
      As[(ml * 4 + 3) * 68 + row] = v.w;
    }
    {
      const int wk = t >> 4, wc4 = (t & 15) * 4;
      *(float4*)(W0s + wk * 64 + wc4) = *(const float4*)(Wm0 + (m0 + wk) * kM + wc4);
      *(float4*)(W1s + wk * 64 + wc4) = *(const float4*)(Wm1 + (m0 + wk) * kM + wc4);
    }
    __syncthreads();
#pragma unroll
    for (int k = 0; k < 16; ++k) {
      const float4 s4 = *(const float4*)(As + (k * 4 + 0) * 68 + ty * 4);
      const float4 x4 = *(const float4*)(As + (k * 4 + 1) * 68 + ty * 4);
      const float4 y4 = *(const float4*)(As + (k * 4 + 2) * 68 + ty * 4);
      const float4 z4 = *(const float4*)(As + (k * 4 + 3) * 68 + ty * 4);
      const float4 w0 = *(const float4*)(W0s + k * 64 + tx * 4);
      const float4 w1 = *(const float4*)(W1s + k * 64 + tx * 4);
      const float as_[4] = {s4.x, s4.y, s4.z, s4.w};
      const float ax[4]  = {x4.x, x4.y, x4.z, x4.w};
      const float ay[4]  = {y4.x, y4.y, y4.z, y4.w};
      const float az[4]  = {z4.x, z4.y, z4.z, z4.w};
      const float b0[4]  = {w0.x, w0.y, w0.z, w0.w};
      const float b1[4]  = {w1.x, w1.y, w1.z, w1.w};
#pragma unroll
      for (int i = 0; i < 4; ++i)
#pragma unroll
        for (int j = 0; j < 4; ++j) {
          acc0[i][j] = fmaf(as_[i], b0[j], acc0[i][j]);
          acc1[i][j] = fmaf(ax[i],  b1[j], acc1[i][j]);
          acc2[i][j] = fmaf(ay[i],  b1[j], acc2[i][j]);
          acc3[i][j] = fmaf(az[i],  b1[j], acc3[i][j]);
        }
    }
  }
  float ps[4] = {}, pv[4] = {};
#pragma unroll
  for (int i = 0; i < 4; ++i)
#pragma unroll
    for (int j = 0; j < 4; ++j) {
      float4 o;
      o.x = acc0[i][j]; o.y = acc1[i][j]; o.z = acc2[i][j]; o.w = acc3[i][j];
      *(float4*)(y + (size_t)(r0 + ty * 4 + i) * kD + (tx * 4 + j) * 4) = o;
      ps[j] = fmaf(o.x, o.x, ps[j]);
      pv[j] += fmaf(o.y, o.y, fmaf(o.z, o.z, o.w * o.w));
    }
  __syncthreads();
  float* red = smem;
#pragma unroll
  for (int j = 0; j < 4; ++j) red[ty * 64 + tx * 4 + j] = ps[j];
  __syncthreads();
  if (t < 64) {
    float s = 0;
#pragma unroll
    for (int k = 0; k < 16; ++k) s += red[k * 64 + t];
    atomicAdd(&stats[t], s);
  }
  __syncthreads();
#pragma unroll
  for (int j = 0; j < 4; ++j) red[ty * 64 + tx * 4 + j] = pv[j];
  __syncthreads();
  if (t < 64) {
    float s = 0;
#pragma unroll
    for (int k = 0; k < 16; ++k) s += red[k * 64 + t];
    atomicAdd(&stats[64 + t], s);
  }
}

// ---------------------------------------------------------------- BN + norm-activation + residual
__global__ void k_bnact(const float* __restrict__ y, const float* __restrict__ stats,
    const float* __restrict__ g0, const float* __restrict__ g1, float* __restrict__ h) {
  const int idx = blockIdx.x * 256 + threadIdx.x;  // r*64 + m
  const int m = idx & 63;
  const float inv0 = g0[m] / sqrtf(stats[m] * (1.0f / 65536.0f) + kEps);
  const float inv1 = g1[m] / sqrtf(stats[64 + m] * (1.0f / 65536.0f) + kEps);
  const float4 v = ((const float4*)y)[idx];
  const float s = v.x * inv0;
  const float vx = v.y * inv1, vy = v.z * inv1, vz = v.w * inv1;
  const float so = s * sigmoidf(fabsf(s));
  const float vn = sqrtf(fmaf(vx, vx, fmaf(vy, vy, vz * vz)) + kEps);
  const float gv = sigmoidf(vn);
  float4 hv = ((float4*)h)[idx];
  hv.x += so;
  hv.y += vx * gv; hv.z += vy * gv; hv.w += vz * gv;
  ((float4*)h)[idx] = hv;
}

// ---------------------------------------------------------------- mean-pool + einsum
__global__ __launch_bounds__(256) void k_pool(const float* __restrict__ h,
    const float* __restrict__ w_out, float* __restrict__ out) {
  __shared__ float r0s[256], r1s[256], r2s[256];
  const int b = blockIdx.x;
  const int t = threadIdx.x;
  float p0 = 0, p1 = 0, p2 = 0;
  for (int idx = t; idx < kN * kM; idx += 256) {
    const int m = idx & 63;
    const float4 v = ((const float4*)h)[(size_t)b * (kN * kM) + idx];
    const float w = w_out[m];
    p0 = fmaf(v.y, w, p0);
    p1 = fmaf(v.z, w, p1);
    p2 = fmaf(v.w, w, p2);
  }
  r0s[t] = p0; r1s[t] = p1; r2s[t] = p2;
  __syncthreads();
  for (int s = 128; s > 0; s >>= 1) {
    if (t < s) { r0s[t] += r0s[t + s]; r1s[t] += r1s[t + s]; r2s[t] += r2s[t + s]; }
    __syncthreads();
  }
  if (t == 0) {
    out[b * 3 + 0] = r0s[0] * (1.0f / kN);
    out[b * 3 + 1] = r1s[0] * (1.0f / kN);
    out[b * 3 + 2] = r2s[0] * (1.0f / kN);
  }
}

} // namespace

extern "C" void kernel_launch(void* const* d_in, const int* in_sizes, int n_in,
                              void* d_out, int out_size, void* d_ws, size_t ws_size,
                              hipStream_t stream) {
  const float* x       = (const float*)d_in[0];
  const float* tok_emb = (const float*)d_in[1];
  const float* Wf      = (const float*)d_in[2];
  const float* wv      = (const float*)d_in[3];
  const float* w_out   = (const float*)d_in[4];

  float* ws    = (float*)d_ws;
  float* h     = ws;                               // 64*1024*256      = 16,777,216
  float* qt    = h   + (size_t)16777216;           // 64*360*1024     = 23,592,960
  float* kvt   = qt  + (size_t)23592960;           //                 = 23,592,960
  float* s0    = kvt + (size_t)23592960;           // 1024*64         =     65,536
  float* kf    = s0  + (size_t)65536;              // 360*1024*2      =    737,280
  float* stats = kf  + (size_t)737280;             // 3*128
  float* y     = qt;                               // alias: q_t dead when y is live

  k_zero<<<1, 384, 0, stream>>>(stats);
  k_s0<<<kN, 64, 0, stream>>>(tok_emb, Wf, s0);
  k_h0<<<(65536 * 64) / 256, 256, 0, stream>>>(x, wv, s0, h);

  for (int l = 0; l < 3; ++l) {
    const float* Wq   = (const float*)d_in[5 + 9 * l + 0];
    const float* Wk   = (const float*)d_in[5 + 9 * l + 1];
    const float* Wv   = (const float*)d_in[5 + 9 * l + 2];
    const float* filt = (const float*)d_in[5 + 9 * l + 3];
    const float* Wo   = (const float*)d_in[5 + 9 * l + 4];
    const float* Wm0  = (const float*)d_in[5 + 9 * l + 5];
    const float* Wm1  = (const float*)d_in[5 + 9 * l + 6];
    const float* g0   = (const float*)d_in[5 + 9 * l + 7];
    const float* g1   = (const float*)d_in[5 + 9 * l + 8];
    const int H = (l == 2) ? 160 : 360;
    float* st = stats + l * 128;

    k_kf<<<H, 256, 0, stream>>>(filt, H, (float2*)kf);
    k_qkv<<<dim3(1024, (H + 63) / 64), 256, 0, stream>>>(h, Wq, Wk, Wv, H, qt, kvt);
    k_conv<<<64 * H, 256, 0, stream>>>(kvt, (const float2*)kf, H);
    k_mix<<<dim3(1024, 4), 256, 0, stream>>>(qt, kvt, Wo, H, h);
    k_reg<<<1024, 256, 0, stream>>>(h, Wm0, Wm1, y, st);
    k_bnact<<<(65536 * 64) / 256, 256, 0, stream>>>(y, st, g0, g1, h);
  }

  k_pool<<<64, 256, 0, stream>>>(h, w_out, (float*)d_out);
}